// Round 13
// baseline (968.266 us; speedup 1.0000x reference)
//
#include <hip/hip_runtime.h>
#include <cstdint>
#include <cstddef>

#define TT 4
#define BB 8
#define CC 256
#define NN 1024
#define HEADS 8
#define DD 32

typedef __attribute__((ext_vector_type(4))) float f32x4;
typedef __attribute__((ext_vector_type(8))) short s16x8;
typedef unsigned short u16;
typedef unsigned int   u32;

__device__ __forceinline__ u16 bf16_rne(float x) {
    u32 u = __float_as_uint(x);
    return (u16)((u + 0x7FFFu + ((u >> 16) & 1u)) >> 16);
}
__device__ __forceinline__ float bf16f(u16 h) {
    return __uint_as_float(((u32)h) << 16);
}

// ---- prep: split f32 array into (hi, lo) bf16 planes, vectorized ----
__global__ __launch_bounds__(256) void prep_split(
    const float* __restrict__ src, u16* __restrict__ h, u16* __restrict__ l, int n4)
{
    for (int i = blockIdx.x * 256 + threadIdx.x; i < n4; i += gridDim.x * 256) {
        float4 v = reinterpret_cast<const float4*>(src)[i];
        ushort4 hh, ll;
        const float* vp = (const float*)&v;
#pragma unroll
        for (int e = 0; e < 4; ++e) {
            u16 hb = bf16_rne(vp[e]);
            ((u16*)&hh)[e] = hb;
            ((u16*)&ll)[e] = bf16_rne(vp[e] - bf16f(hb));
        }
        reinterpret_cast<ushort4*>(h)[i] = hh;
        reinterpret_cast<ushort4*>(l)[i] = ll;
    }
}

// ---- prep: per-channel BN constants (f32 fast path + f64 scale for recompute) ----
// channel map: [0,256)q [256,512)k [512,768)v [768,1024)proj [1024,2048)mlp1 [2048,2304)mlp2
__global__ __launch_bounds__(256) void prep_bn(
    const float* qbn, const float* kbn, const float* vbn, const float* pbn,
    const float* m1bn, const float* m2bn,
    const float* pb, const float* m1b, const float* m2b,
    float2* __restrict__ bnf, double* __restrict__ bnd)
{
    int c = blockIdx.x * 256 + threadIdx.x;
    if (c >= 2304) return;
    const float* bn; int ch, O; double bi = 0.0;
    if (c < 1024) {
        int s = c >> 8; ch = c & 255; O = 256;
        bn = s == 0 ? qbn : s == 1 ? kbn : s == 2 ? vbn : pbn;
        if (s == 3) bi = (double)pb[ch];
    } else if (c < 2048) { ch = c - 1024; O = 1024; bn = m1bn; bi = (double)m1b[ch]; }
    else                 { ch = c - 2048; O = 256;  bn = m2bn; bi = (double)m2b[ch]; }
    double g = (double)bn[0*O+ch], be = (double)bn[1*O+ch];
    double mu = (double)bn[2*O+ch], var = (double)bn[3*O+ch];
    double sd = g / sqrt(var + 1e-5);
    bnf[c] = make_float2((float)sd, (float)((bi - mu) * sd + be));
    bnd[c] = sd;
}

// ---- fused conv1x1 + BN + LIF, bf16-split MFMA, pre-converted operands ----
// Block 64o x 64n, 4 waves (wave = timestep). acc[4][4] f32x4 per wave.
// LDS tiles [row][32k] ushort with 3-term XOR swizzle
//   p(k,r) = (k>>3) ^ ((r>>1)&3) ^ ((r>>3)&3), ushort idx = p*8 + (k&7)
// -> frag reads (b128) 2-way bank = free; staged writes (b32 pairs) ~4-way.
// Staging: pure vector copies from pre-split bf16 planes; zero convert VALU.
// EPS-screen + exact f64 recompute identical to round 12 (validated absmax 0.0).
// OUT_MODE: 0 = f32 spikes (qkv) | 1 = proj (f32 x_new + bf16 hi/lo planes, +base)
//           2 = bf16 spikes (mlp1) | 3 = f32 + base (mlp2)
template<bool SPLIT_IN, int CIN, int OUT_MODE, bool TRIPLE, bool EXACT_BF16, int O>
__global__ __launch_bounds__(256, 2) void conv_kernel(
    const u16* __restrict__ XH, const u16* __restrict__ XL,
    const void* __restrict__ Xe_,
    const u16* __restrict__ WH0, const u16* __restrict__ WL0,
    const u16* __restrict__ WH1, const u16* __restrict__ WL1,
    const u16* __restrict__ WH2, const u16* __restrict__ WL2,
    const float* __restrict__ Wx0, const float* __restrict__ Wx1,
    const float* __restrict__ Wx2,
    const float* __restrict__ bnr0, const float* __restrict__ bnr1,
    const float* __restrict__ bnr2, const float* __restrict__ bias,
    const float2* __restrict__ bnf, const double* __restrict__ bnd,
    void* __restrict__ O0_, void* __restrict__ O1_, void* __restrict__ O2_,
    u16* __restrict__ OutH, u16* __restrict__ OutL,
    const float* __restrict__ base)
{
    constexpr int PL = SPLIT_IN ? 2 : 1;
    constexpr float EPS = 3e-4f;
    __shared__ __align__(16) u16 Wt[2][2][64][32];        // 16 KB
    __shared__ __align__(16) u16 Xt[2][PL][TT][64][32];   // 64 / 32 KB
    float* pre = (float*)&Xt[0][0][0][0][0];              // [2][64][64] f32 overlay

    const int tid  = threadIdx.x;
    const int lane = tid & 63;
    const int wave = tid >> 6;          // == timestep t
    const int lr   = lane & 15;
    const int lk   = lane >> 4;
    const int n0 = blockIdx.x * 64;
    const int b  = blockIdx.z;

    int o0, cofs;
    const u16 *WH, *WL; const float *Wx, *bnr;
    void* Out_;
    if constexpr (TRIPLE) {
        const int sel = blockIdx.y >> 2;
        o0 = (blockIdx.y & 3) * 64;
        WH = sel==0?WH0:sel==1?WH1:WH2;  WL = sel==0?WL0:sel==1?WL1:WL2;
        Wx = sel==0?Wx0:sel==1?Wx1:Wx2;  bnr = sel==0?bnr0:sel==1?bnr1:bnr2;
        Out_ = sel==0?O0_:sel==1?O1_:O2_;
        cofs = sel * 256;
    } else {
        o0 = blockIdx.y * 64; WH = WH0; WL = WL0; Wx = Wx0; bnr = bnr0;
        Out_ = O0_; cofs = 0;
    }

    f32x4 acc[4][4];
#pragma unroll
    for (int mf = 0; mf < 4; ++mf)
#pragma unroll
        for (int nf = 0; nf < 4; ++nf)
            acc[mf][nf] = (f32x4){0.f, 0.f, 0.f, 0.f};

    // staging thread mappings
    const int wo = tid >> 2, wg = tid & 3;            // W: 64 o x 4 k-octets
    const int tp = tid >> 7;                           // t-pair
    const int kp = (tid >> 3) & 15;                    // k-pair (k = 2kp, 2kp+1)
    const int n8b = (tid & 7) * 8;

    s16x8 rWH, rWL;
    s16x8 rxh[2][2];                                   // [dt][k of pair]
    s16x8 rxl[2][2];

    auto issue = [&](int c0) {
        rWH = *(const s16x8*)&WH[(size_t)(o0 + wo) * CIN + c0 + wg * 8];
        rWL = *(const s16x8*)&WL[(size_t)(o0 + wo) * CIN + c0 + wg * 8];
#pragma unroll
        for (int dt = 0; dt < 2; ++dt) {
            const size_t xb =
                (((size_t)(tp * 2 + dt) * BB + b) * CIN + c0 + 2 * kp) * NN + n0 + n8b;
            rxh[dt][0] = *(const s16x8*)&XH[xb];
            rxh[dt][1] = *(const s16x8*)&XH[xb + NN];
            if constexpr (SPLIT_IN) {
                rxl[dt][0] = *(const s16x8*)&XL[xb];
                rxl[dt][1] = *(const s16x8*)&XL[xb + NN];
            }
        }
    };
    auto writeT = [&](int buf) {
        const int wu = (wg ^ ((wo >> 1) & 3) ^ ((wo >> 3) & 3)) * 8;
        *(s16x8*)&Wt[buf][0][wo][wu] = rWH;
        *(s16x8*)&Wt[buf][1][wo][wu] = rWL;
#pragma unroll
        for (int dt = 0; dt < 2; ++dt) {
            const int t = tp * 2 + dt;
#pragma unroll
            for (int j = 0; j < 8; ++j) {
                const int n = n8b + j;
                const int ui = (((kp >> 2) ^ ((n >> 1) & 3) ^ ((n >> 3) & 3)) * 4) + (kp & 3);
                u32 vh = (u32)(u16)rxh[dt][0][j] | ((u32)(u16)rxh[dt][1][j] << 16);
                ((u32*)&Xt[buf][0][t][n][0])[ui] = vh;
                if constexpr (SPLIT_IN) {
                    u32 vl = (u32)(u16)rxl[dt][0][j] | ((u32)(u16)rxl[dt][1][j] << 16);
                    ((u32*)&Xt[buf][PL - 1][t][n][0])[ui] = vl;
                }
            }
        }
    };

    issue(0);
    writeT(0);
    __syncthreads();

    int cur = 0;
    for (int c0 = 32; c0 <= CIN; c0 += 32) {
        const bool hn = (c0 < CIN);
        if (hn) issue(c0);
        __builtin_amdgcn_s_setprio(1);
        s16x8 aH[4], aL[4], bH[4], bL[4];
#pragma unroll
        for (int mf = 0; mf < 4; ++mf) {
            const int o = mf * 16 + lr;
            const int u = (lk ^ ((o >> 1) & 3) ^ ((o >> 3) & 3)) * 8;
            aH[mf] = *(const s16x8*)&Wt[cur][0][o][u];
            aL[mf] = *(const s16x8*)&Wt[cur][1][o][u];
        }
#pragma unroll
        for (int nf = 0; nf < 4; ++nf) {
            const int n = nf * 16 + lr;
            const int u = (lk ^ ((n >> 1) & 3) ^ ((n >> 3) & 3)) * 8;
            bH[nf] = *(const s16x8*)&Xt[cur][0][wave][n][u];
            if constexpr (SPLIT_IN)
                bL[nf] = *(const s16x8*)&Xt[cur][PL - 1][wave][n][u];
        }
#pragma unroll
        for (int mf = 0; mf < 4; ++mf)
#pragma unroll
            for (int nf = 0; nf < 4; ++nf) {
                acc[mf][nf] = __builtin_amdgcn_mfma_f32_16x16x32_bf16(
                    aH[mf], bH[nf], acc[mf][nf], 0, 0, 0);
                acc[mf][nf] = __builtin_amdgcn_mfma_f32_16x16x32_bf16(
                    aL[mf], bH[nf], acc[mf][nf], 0, 0, 0);
                if constexpr (SPLIT_IN)
                    acc[mf][nf] = __builtin_amdgcn_mfma_f32_16x16x32_bf16(
                        aH[mf], bL[nf], acc[mf][nf], 0, 0, 0);
            }
        __builtin_amdgcn_s_setprio(0);
        if (hn) writeT(cur ^ 1);
        __syncthreads();
        cur ^= 1;
    }

    // ---- epilogue ----
    const int nl = tid & 63;
    const int og = wave;

    auto dump = [&](int slot) {
#pragma unroll
        for (int mf = 0; mf < 4; ++mf)
#pragma unroll
            for (int nf = 0; nf < 4; ++nf)
#pragma unroll
                for (int r = 0; r < 4; ++r)
                    pre[(size_t)(slot * 64 + mf * 16 + lk * 4 + r) * 64
                        + nf * 16 + lr] = acc[mf][nf][r];
    };

    float2 sc[16];
#pragma unroll
    for (int i = 0; i < 16; ++i) sc[i] = bnf[cofs + o0 + og * 16 + i];

    auto wout = [&](int t, int i, float s) {
        const int o = o0 + og * 16 + i;
        const size_t idx = (((size_t)t * BB + b) * O + o) * NN + n0 + nl;
        if constexpr (OUT_MODE == 0) ((float*)Out_)[idx] = s;
        else if constexpr (OUT_MODE == 1) {
            float xn = base[idx] + s;
            ((float*)Out_)[idx] = xn;
            u16 hh = bf16_rne(xn);
            OutH[idx] = hh;
            OutL[idx] = bf16_rne(xn - bf16f(hh));
        } else if constexpr (OUT_MODE == 2)
            ((u16*)Out_)[idx] = (s > 0.5f) ? (u16)0x3F80 : (u16)0;
        else ((float*)Out_)[idx] = base[idx] + s;
    };

    unsigned flags = 0;
    float vst[16];

    if (wave < 2) dump(wave);
    __syncthreads();
#pragma unroll
    for (int i = 0; i < 16; ++i) {
        float v = 0.f;
#pragma unroll
        for (int t = 0; t < 2; ++t) {
            float val = fmaf(pre[(size_t)(t * 64 + og * 16 + i) * 64 + nl], sc[i].x, sc[i].y);
            v = v + (val - v) * 0.5f;
            if (fabsf(v - 1.0f) < EPS) flags |= (1u << i);
            float s = (v >= 1.0f) ? 1.f : 0.f;
            wout(t, i, s);
            v *= (1.f - s);
        }
        vst[i] = v;
    }
    __syncthreads();
    if (wave >= 2) dump(wave - 2);
    __syncthreads();
#pragma unroll
    for (int i = 0; i < 16; ++i) {
        float v = vst[i];
#pragma unroll
        for (int t = 2; t < 4; ++t) {
            float val = fmaf(pre[(size_t)((t - 2) * 64 + og * 16 + i) * 64 + nl], sc[i].x, sc[i].y);
            v = v + (val - v) * 0.5f;
            if (fabsf(v - 1.0f) < EPS) flags |= (1u << i);
            float s = (v >= 1.0f) ? 1.f : 0.f;
            wout(t, i, s);
            v *= (1.f - s);
        }
    }

    // ---- exact f64 recompute of flagged columns (rare) ----
    if (flags) {
#pragma unroll 1
        for (int i = 0; i < 16; ++i) {
            if (!(flags & (1u << i))) continue;
            const int o = o0 + og * 16 + i;
            const int n = n0 + nl;
            double s0 = 0.0, s1 = 0.0, s2 = 0.0, s3 = 0.0;
#pragma unroll 2
            for (int k = 0; k < CIN; ++k) {
                const double w = (double)Wx[(size_t)o * CIN + k];
                const size_t xr = (size_t)k * NN + n;
                double x0, x1, x2, x3;
                if constexpr (EXACT_BF16) {
                    const u16* Xe = (const u16*)Xe_;
                    x0 = (double)bf16f(Xe[((size_t)(0 * BB + b) * CIN) * NN + xr]);
                    x1 = (double)bf16f(Xe[((size_t)(1 * BB + b) * CIN) * NN + xr]);
                    x2 = (double)bf16f(Xe[((size_t)(2 * BB + b) * CIN) * NN + xr]);
                    x3 = (double)bf16f(Xe[((size_t)(3 * BB + b) * CIN) * NN + xr]);
                } else {
                    const float* Xe = (const float*)Xe_;
                    x0 = (double)Xe[((size_t)(0 * BB + b) * CIN) * NN + xr];
                    x1 = (double)Xe[((size_t)(1 * BB + b) * CIN) * NN + xr];
                    x2 = (double)Xe[((size_t)(2 * BB + b) * CIN) * NN + xr];
                    x3 = (double)Xe[((size_t)(3 * BB + b) * CIN) * NN + xr];
                }
                s0 += w * x0; s1 += w * x1; s2 += w * x2; s3 += w * x3;
            }
            double sums[4] = {s0, s1, s2, s3};
            const double scale = bnd[cofs + o];
            const double be = (double)bnr[1 * O + o];
            const double mu = (double)bnr[2 * O + o];
            double bi = 0.0;
            if constexpr (OUT_MODE != 0) bi = (double)bias[o];
            double v = 0.0;
#pragma unroll
            for (int t = 0; t < TT; ++t) {
                const double val = (sums[t] + bi - mu) * scale + be;
                v = v + (val - v) * 0.5;
                const double sd = (v >= 1.0) ? 1.0 : 0.0;
                const size_t idx = (((size_t)t * BB + b) * O + o) * NN + n0 + nl;
                if constexpr (OUT_MODE == 0) ((float*)Out_)[idx] = (float)sd;
                else if constexpr (OUT_MODE == 1) {
                    float xn = (float)((double)base[idx] + sd);
                    ((float*)Out_)[idx] = xn;
                    u16 hh = bf16_rne(xn);
                    OutH[idx] = hh;
                    OutL[idx] = bf16_rne(xn - bf16f(hh));
                } else if constexpr (OUT_MODE == 2)
                    ((u16*)Out_)[idx] = (sd > 0.5) ? (u16)0x3F80 : (u16)0;
                else ((float*)Out_)[idx] = (float)((double)base[idx] + sd);
                v = v * (1.0 - sd);
            }
        }
    }
}

// kv[t,b,h,d,e] = sum_n k[...] * v[...]  (exact integer arithmetic in fp32)
__global__ __launch_bounds__(256) void kv_kernel(
    const float* __restrict__ k_s, const float* __restrict__ v_s,
    float* __restrict__ kv)
{
    const int blk = blockIdx.x;
    const int h = blk & 7;
    const int m = blk >> 3;
    __shared__ float ks[32][65];
    __shared__ float vs[32][65];
    const int tid = threadIdx.x;
    const int d = tid >> 3;
    const int e0 = (tid & 7) * 4;
    float acc[4] = {0.f, 0.f, 0.f, 0.f};
    const size_t basek = ((size_t)m * CC + h * DD) * NN;
    for (int nc = 0; nc < NN; nc += 64) {
        for (int i = tid; i < 2048; i += 256) {
            int r = i >> 6, nl = i & 63;
            ks[r][nl] = k_s[basek + (size_t)r * NN + nc + nl];
            vs[r][nl] = v_s[basek + (size_t)r * NN + nc + nl];
        }
        __syncthreads();
        for (int nl = 0; nl < 64; ++nl) {
            float kd = ks[d][nl];
#pragma unroll
            for (int j = 0; j < 4; ++j) acc[j] += kd * vs[e0 + j][nl];
        }
        __syncthreads();
    }
#pragma unroll
    for (int j = 0; j < 4; ++j)
        kv[(size_t)blk * 1024 + d * 32 + e0 + j] = acc[j];
}

// a = 0.125 * q @ kv -> LIF(v_th=0.5); exact dyadic fp32; writes bf16 spikes.
__global__ __launch_bounds__(256) void attn_a_lif(
    const float* __restrict__ q_s, const float* __restrict__ kv,
    u16* __restrict__ a_s)
{
    const int tid = threadIdx.x;
    const int n = blockIdx.x * 256 + tid;
    const int c = blockIdx.y;
    const int b = blockIdx.z;
    const int h = c >> 5;
    const int e = c & 31;
    __shared__ float kvs[TT][32];
    if (tid < 128) {
        int t = tid >> 5, d2 = tid & 31;
        kvs[t][d2] = kv[(((size_t)t * BB + b) * HEADS + h) * 1024 + d2 * 32 + e];
    }
    __syncthreads();
    float val[TT];
#pragma unroll
    for (int t = 0; t < TT; ++t) {
        float s = 0.f;
        const size_t qb = (((size_t)t * BB + b) * CC + h * DD) * NN + n;
#pragma unroll 8
        for (int d2 = 0; d2 < 32; ++d2)
            s += q_s[qb + (size_t)d2 * NN] * kvs[t][d2];
        val[t] = s * 0.125f;
    }
    float v = 0.f;
#pragma unroll
    for (int t = 0; t < TT; ++t) {
        v = v + (val[t] - v) * 0.5f;
        float s = (v >= 0.5f) ? 1.f : 0.f;
        a_s[(((size_t)t * BB + b) * CC + c) * NN + n] = (s > 0.5f) ? (u16)0x3F80 : (u16)0;
        v = v * (1.f - s);
    }
}

extern "C" void kernel_launch(void* const* d_in, const int* in_sizes, int n_in,
                              void* d_out, int out_size, void* d_ws, size_t ws_size,
                              hipStream_t stream)
{
    const float* x       = (const float*)d_in[0];
    const float* q_w     = (const float*)d_in[1];
    const float* q_bn    = (const float*)d_in[2];
    const float* k_w     = (const float*)d_in[3];
    const float* k_bn    = (const float*)d_in[4];
    const float* v_w     = (const float*)d_in[5];
    const float* v_bn    = (const float*)d_in[6];
    const float* proj_w  = (const float*)d_in[7];
    const float* proj_b  = (const float*)d_in[8];
    const float* proj_bn = (const float*)d_in[9];
    const float* mlp1_w  = (const float*)d_in[10];
    const float* mlp1_b  = (const float*)d_in[11];
    const float* mlp1_bn = (const float*)d_in[12];
    const float* mlp2_w  = (const float*)d_in[13];
    const float* mlp2_b  = (const float*)d_in[14];
    const float* mlp2_bn = (const float*)d_in[15];

    const size_t SZ = (size_t)TT * BB * CC * NN;   // 8388608 elements
    char* ws = (char*)d_ws;
    float* q_s   = (float*)(ws);                    // SZ f32   (later: h1 part)
    float* k_s   = (float*)(ws + SZ * 4);
    float* v_s   = (float*)(ws + SZ * 8);
    u16*   xh    = (u16*)  (ws + SZ * 12);
    u16*   xl    = (u16*)  (ws + SZ * 14);
    u16*   a_s   = (u16*)  (ws + SZ * 16);
    float* kvb   = (float*)(ws + SZ * 18);          // 1 MB
    // overlays (timeline-safe):
    u16*   h1    = (u16*)  (ws);                    // SZ*4 elems bf16 = q_s+k_s
    u16*   xnh   = (u16*)  (ws + SZ * 8);           // overlays v_s
    u16*   xnl   = (u16*)  (ws + SZ * 10);
    float* x_new = (float*)(ws + SZ * 12);          // overlays xh+xl
    char* wp = ws + SZ * 18 + (size_t)262144 * 4;
    u16* qh  = (u16*)wp; wp += 65536 * 2;  u16* ql  = (u16*)wp; wp += 65536 * 2;
    u16* kh  = (u16*)wp; wp += 65536 * 2;  u16* kl  = (u16*)wp; wp += 65536 * 2;
    u16* vh  = (u16*)wp; wp += 65536 * 2;  u16* vl  = (u16*)wp; wp += 65536 * 2;
    u16* ph  = (u16*)wp; wp += 65536 * 2;  u16* pl  = (u16*)wp; wp += 65536 * 2;
    u16* m1h = (u16*)wp; wp += 262144 * 2; u16* m1l = (u16*)wp; wp += 262144 * 2;
    u16* m2h = (u16*)wp; wp += 262144 * 2; u16* m2l = (u16*)wp; wp += 262144 * 2;
    float2* bnf = (float2*)wp; wp += 2304 * 8;
    double* bnd = (double*)wp;

    dim3 blk(256);

    // prep: split x + all weights into bf16 hi/lo planes, BN constants
    prep_split<<<dim3(4096), blk, 0, stream>>>(x, xh, xl, (int)(SZ / 4));
    prep_split<<<dim3(64),  blk, 0, stream>>>(q_w,    qh,  ql,  65536 / 4);
    prep_split<<<dim3(64),  blk, 0, stream>>>(k_w,    kh,  kl,  65536 / 4);
    prep_split<<<dim3(64),  blk, 0, stream>>>(v_w,    vh,  vl,  65536 / 4);
    prep_split<<<dim3(64),  blk, 0, stream>>>(proj_w, ph,  pl,  65536 / 4);
    prep_split<<<dim3(256), blk, 0, stream>>>(mlp1_w, m1h, m1l, 262144 / 4);
    prep_split<<<dim3(256), blk, 0, stream>>>(mlp2_w, m2h, m2l, 262144 / 4);
    prep_bn<<<dim3(9), blk, 0, stream>>>(q_bn, k_bn, v_bn, proj_bn, mlp1_bn,
                                         mlp2_bn, proj_b, mlp1_b, mlp2_b, bnf, bnd);

    // qkv (fused): x(split) -> f32 spike trains
    conv_kernel<true, 256, 0, true, false, 256>
        <<<dim3(16, 12, 8), blk, 0, stream>>>(
        xh, xl, x, qh, ql, kh, kl, vh, vl, q_w, k_w, v_w,
        q_bn, k_bn, v_bn, nullptr, bnf, bnd,
        q_s, k_s, v_s, nullptr, nullptr, nullptr);

    // attention
    kv_kernel<<<dim3(TT * BB * HEADS), blk, 0, stream>>>(k_s, v_s, kvb);
    attn_a_lif<<<dim3(4, 256, 8), blk, 0, stream>>>(q_s, kvb, a_s);

    // proj: a_s(bf16 spikes) -> x_new f32 + (xnh,xnl) bf16 planes
    conv_kernel<false, 256, 1, false, true, 256>
        <<<dim3(16, 4, 8), blk, 0, stream>>>(
        a_s, nullptr, a_s, ph, pl, nullptr, nullptr, nullptr, nullptr,
        proj_w, nullptr, nullptr, proj_bn, nullptr, nullptr, proj_b,
        bnf + 768, bnd + 768, x_new, nullptr, nullptr, xnh, xnl, x);

    // mlp1: x_new(split planes) -> h1 bf16 spikes
    conv_kernel<true, 256, 2, false, false, 1024>
        <<<dim3(16, 16, 8), blk, 0, stream>>>(
        xnh, xnl, x_new, m1h, m1l, nullptr, nullptr, nullptr, nullptr,
        mlp1_w, nullptr, nullptr, mlp1_bn, nullptr, nullptr, mlp1_b,
        bnf + 1024, bnd + 1024, h1, nullptr, nullptr, nullptr, nullptr, nullptr);

    // mlp2: h1(bf16 spikes) -> d_out (+x_new residual)
    conv_kernel<false, 1024, 3, false, true, 256>
        <<<dim3(16, 4, 8), blk, 0, stream>>>(
        h1, nullptr, h1, m2h, m2l, nullptr, nullptr, nullptr, nullptr,
        mlp2_w, nullptr, nullptr, mlp2_bn, nullptr, nullptr, mlp2_b,
        bnf + 2048, bnd + 2048, d_out, nullptr, nullptr, nullptr, nullptr, x_new);
}